// Round 4
// baseline (85.180 us; speedup 1.0000x reference)
//
#include <hip/hip_runtime.h>

#define NCAPS 1152
#define KD 8
#define JD 10
#define DD 16
#define BATCH 512
#define BTILE 64

typedef float f32x4 __attribute__((ext_vector_type(4)));

// out[b,n,j,d] = sum_k W[n,j,d,k] * pc[b,n,k],  pc = squash(x[b,n,:])
// Block: 320 threads = 8 batch-groups x 40 (j,dq) combos. W held in registers.
// 1D grid of 9216 with XCD-aware swizzle: XCD (bid&7) owns n in [xcd*144, xcd*144+144).
__global__ __launch_bounds__(320) void caps_kernel(
    const float* __restrict__ x,   // [512, 1152*8]
    const float* __restrict__ W,   // [1152,10,16,8]
    float* __restrict__ out)       // [512,1152,10,16]
{
    const int bid   = blockIdx.x;          // 0..9215
    const int local = bid >> 3;            // 0..1151 (per-XCD sequence)
    const int n     = (bid & 7) * 144 + (local >> 3);  // contiguous n-range per XCD
    const int bb    = local & 7;           // batch tile 0..7
    const int t     = threadIdx.x;         // 0..319

    __shared__ float pcs[BTILE][KD];   // squashed primary caps for this tile

    // ---- squash: one thread per batch row (first wave) ----
    if (t < BTILE) {
        int b = bb * BTILE + t;
        const float* xp = x + (size_t)b * (NCAPS * KD) + n * KD;
        float4 v0 = *(const float4*)(xp);
        float4 v1 = *(const float4*)(xp + 4);
        float sq = v0.x * v0.x + v0.y * v0.y + v0.z * v0.z + v0.w * v0.w
                 + v1.x * v1.x + v1.y * v1.y + v1.z * v1.z + v1.w * v1.w;
        float scale = sq / ((1.0f + sq) * sqrtf(sq + 1e-7f));
        pcs[t][0] = v0.x * scale;
        pcs[t][1] = v0.y * scale;
        pcs[t][2] = v0.z * scale;
        pcs[t][3] = v0.w * scale;
        pcs[t][4] = v1.x * scale;
        pcs[t][5] = v1.y * scale;
        pcs[t][6] = v1.z * scale;
        pcs[t][7] = v1.w * scale;
    }

    // ---- load this thread's W fragment into registers (L2-resident per XCD) ----
    const int c  = t % 40;       // (j,dq) combo
    const int g  = t / 40;       // batch group 0..7
    const int j  = c >> 2;
    const int dq = c & 3;
    const float* wp = W + (size_t)n * (JD * DD * KD) + j * (DD * KD) + dq * 4 * KD;
    float4 wA0 = *(const float4*)(wp + 0);
    float4 wB0 = *(const float4*)(wp + 4);
    float4 wA1 = *(const float4*)(wp + 8);
    float4 wB1 = *(const float4*)(wp + 12);
    float4 wA2 = *(const float4*)(wp + 16);
    float4 wB2 = *(const float4*)(wp + 20);
    float4 wA3 = *(const float4*)(wp + 24);
    float4 wB3 = *(const float4*)(wp + 28);

    __syncthreads();

    // ---- 8 batches per thread: broadcast pc from LDS, 32 FMA, 1 store ----
    #pragma unroll
    for (int i = 0; i < 8; ++i) {
        int bl = g * 8 + i;
        float4 p0 = *(const float4*)&pcs[bl][0];
        float4 p1 = *(const float4*)&pcs[bl][4];

        f32x4 acc;
        acc.x = wA0.x*p0.x + wA0.y*p0.y + wA0.z*p0.z + wA0.w*p0.w
              + wB0.x*p1.x + wB0.y*p1.y + wB0.z*p1.z + wB0.w*p1.w;
        acc.y = wA1.x*p0.x + wA1.y*p0.y + wA1.z*p0.z + wA1.w*p0.w
              + wB1.x*p1.x + wB1.y*p1.y + wB1.z*p1.z + wB1.w*p1.w;
        acc.z = wA2.x*p0.x + wA2.y*p0.y + wA2.z*p0.z + wA2.w*p0.w
              + wB2.x*p1.x + wB2.y*p1.y + wB2.z*p1.z + wB2.w*p1.w;
        acc.w = wA3.x*p0.x + wA3.y*p0.y + wA3.z*p0.z + wA3.w*p0.w
              + wB3.x*p1.x + wB3.y*p1.y + wB3.z*p1.z + wB3.w*p1.w;

        int b = bb * BTILE + bl;
        size_t off = (((size_t)b * NCAPS + n) * JD + j) * DD + (dq << 2);
        __builtin_nontemporal_store(acc, (f32x4*)(out + off));
    }
}

extern "C" void kernel_launch(void* const* d_in, const int* in_sizes, int n_in,
                              void* d_out, int out_size, void* d_ws, size_t ws_size,
                              hipStream_t stream) {
    const float* x = (const float*)d_in[0];
    const float* W = (const float*)d_in[1];
    float* out = (float*)d_out;
    caps_kernel<<<NCAPS * (BATCH / BTILE), 320, 0, stream>>>(x, W, out);
}

// Round 5
// 78.743 us; speedup vs baseline: 1.0818x; 1.0818x over previous
//
#include <hip/hip_runtime.h>

#define NCAPS 1152
#define KD 8
#define JD 10
#define DD 16
#define BATCH 512
#define NP 8          // n's per block
#define BT 32         // batches per block
#define NQ (NCAPS / NP)      // 144
#define NBB (BATCH / BT)     // 16

typedef float f32x4 __attribute__((ext_vector_type(4)));

// out[b,n,j,d] = sum_k W[n,j,d,k] * pc[b,n,k],  pc = squash(x[b,n,:])
// Block: 320 threads = 8 n_local x 40 (j,dq) combos; each thread owns one
// (n_l,j,dq) W fragment (32 floats in regs) and loops over 32 batches.
// Within a b-row, the 8-n output slab is 5120 B contiguous and the thread's
// float4 slot = threadIdx -> every wave store is a contiguous aligned 1 KB.
__global__ __launch_bounds__(320) void caps_kernel(
    const float* __restrict__ x,   // [512, 1152*8]
    const float* __restrict__ W,   // [1152,10,16,8]
    float* __restrict__ out)       // [512,1152,10,16]
{
    const int bid = blockIdx.x;        // 0..2303, bb-major (consecutive = same bb)
    const int bb  = bid / NQ;          // 0..15
    const int nq  = bid - bb * NQ;     // 0..143
    const int n0  = nq * NP;
    const int b0  = bb * BT;
    const int t   = threadIdx.x;       // 0..319

    __shared__ float pcs[NP][BT][KD];  // 8 KB

    // ---- squash: threads 0..255 each handle one (b_l, n_l) pair ----
    if (t < BT * NP) {
        int n_l = t & 7;               // fastest -> 8 lanes read 256 B contiguous
        int b_l = t >> 3;
        const float* xp = x + (size_t)(b0 + b_l) * (NCAPS * KD) + (n0 + n_l) * KD;
        float4 v0 = *(const float4*)(xp);
        float4 v1 = *(const float4*)(xp + 4);
        float sq = v0.x * v0.x + v0.y * v0.y + v0.z * v0.z + v0.w * v0.w
                 + v1.x * v1.x + v1.y * v1.y + v1.z * v1.z + v1.w * v1.w;
        float scale = sq / ((1.0f + sq) * sqrtf(sq + 1e-7f));
        float* pp = &pcs[n_l][b_l][0];
        pp[0] = v0.x * scale;  pp[1] = v0.y * scale;
        pp[2] = v0.z * scale;  pp[3] = v0.w * scale;
        pp[4] = v1.x * scale;  pp[5] = v1.y * scale;
        pp[6] = v1.z * scale;  pp[7] = v1.w * scale;
    }

    // ---- this thread's W fragment: (n_l, j, dq), 32 floats, read once ----
    const int n_l = t / 40;
    const int c2  = t - n_l * 40;
    const int j   = c2 >> 2;
    const int dq  = c2 & 3;
    const float* wp = W + (size_t)(n0 + n_l) * (JD * DD * KD) + j * (DD * KD) + dq * 4 * KD;
    float4 wA0 = *(const float4*)(wp + 0);
    float4 wB0 = *(const float4*)(wp + 4);
    float4 wA1 = *(const float4*)(wp + 8);
    float4 wB1 = *(const float4*)(wp + 12);
    float4 wA2 = *(const float4*)(wp + 16);
    float4 wB2 = *(const float4*)(wp + 20);
    float4 wA3 = *(const float4*)(wp + 24);
    float4 wB3 = *(const float4*)(wp + 28);

    __syncthreads();

    // ---- 32 batches: broadcast pc, 32 FMA, one contiguous-per-wave store ----
    // out float offset = b*184320 + n0*160 + 4*t  (slab-internal index == t)
    const float* pbase = &pcs[n_l][0][0];
    size_t rowbase = (size_t)b0 * (NCAPS * JD * DD) + (size_t)n0 * (JD * DD) + 4 * t;
    #pragma unroll 8
    for (int b_l = 0; b_l < BT; ++b_l) {
        float4 p0 = *(const float4*)(pbase + b_l * KD);
        float4 p1 = *(const float4*)(pbase + b_l * KD + 4);

        f32x4 acc;
        acc.x = wA0.x*p0.x + wA0.y*p0.y + wA0.z*p0.z + wA0.w*p0.w
              + wB0.x*p1.x + wB0.y*p1.y + wB0.z*p1.z + wB0.w*p1.w;
        acc.y = wA1.x*p0.x + wA1.y*p0.y + wA1.z*p0.z + wA1.w*p0.w
              + wB1.x*p1.x + wB1.y*p1.y + wB1.z*p1.z + wB1.w*p1.w;
        acc.z = wA2.x*p0.x + wA2.y*p0.y + wA2.z*p0.z + wA2.w*p0.w
              + wB2.x*p1.x + wB2.y*p1.y + wB2.z*p1.z + wB2.w*p1.w;
        acc.w = wA3.x*p0.x + wA3.y*p0.y + wA3.z*p0.z + wA3.w*p0.w
              + wB3.x*p1.x + wB3.y*p1.y + wB3.z*p1.z + wB3.w*p1.w;

        __builtin_nontemporal_store(acc, (f32x4*)(out + rowbase + (size_t)b_l * (NCAPS * JD * DD)));
    }
}

extern "C" void kernel_launch(void* const* d_in, const int* in_sizes, int n_in,
                              void* d_out, int out_size, void* d_ws, size_t ws_size,
                              hipStream_t stream) {
    const float* x = (const float*)d_in[0];
    const float* W = (const float*)d_in[1];
    float* out = (float*)d_out;
    caps_kernel<<<NQ * NBB, 320, 0, stream>>>(x, W, out);
}